// Round 2
// baseline (476.777 us; speedup 1.0000x reference)
//
#include <hip/hip_runtime.h>

#define T_TOK 16384
#define H_DIM 2048
#define E_EXP 64
#define K_TOP 2
#define AUX_COEFF 0.01f
#define Z_COEFF 0.001f

#define NT 8                        // tokens per wave
#define NWAVES 4
#define BLOCK (NWAVES * 64)
#define TOK_PER_BLK (NT * NWAVES)   // 32
#define KC 128                      // H-chunk staged in LDS
#define NCHUNK (H_DIM / KC)         // 16
#define NBLK (T_TOK / TOK_PER_BLK)  // 512
#define PART_STRIDE 132             // 64 sumprob + 64 count + 1 lse2 (+pad)
// d_ws usage: NBLK * PART_STRIDE * 4 B = 264 KB

__device__ __forceinline__ void load_lds16(const float* g, float* l) {
  __builtin_amdgcn_global_load_lds(
      (const __attribute__((address_space(1))) void*)g,
      (__attribute__((address_space(3))) void*)l, 16, 0, 0);
}

__global__ __launch_bounds__(BLOCK, 2) void router_main(
    const float* __restrict__ x, const float* __restrict__ w,
    float* __restrict__ out, float* __restrict__ part) {
  __shared__ float wlds[2][KC * E_EXP];      // 2 x 32 KB
  __shared__ float rsp[NWAVES][E_EXP];
  __shared__ float rcn[NWAVES][E_EXP];
  __shared__ float rz[NWAVES];

  const int tid = threadIdx.x;
  const int lane = tid & 63;
  const int wv = tid >> 6;
  const int t0 = blockIdx.x * TOK_PER_BLK + wv * NT;
  const float* xw = x + (size_t)t0 * H_DIM;

  float acc[NT];
#pragma unroll
  for (int i = 0; i < NT; ++i) acc[i] = 0.f;

  // stage chunk 0 -> buf 0 (per-wave: 8 x 1KB linear LDS segments)
#pragma unroll
  for (int j = 0; j < 8; ++j) {
    const int seg = wv * 8 + j;
    load_lds16(w + seg * 256 + lane * 4, &wlds[0][seg * 256]);
  }

  int cur = 0;
  for (int c = 0; c < NCHUNK; ++c) {
    __syncthreads();  // compiler drains vmcnt before s_barrier -> staging done
    if (c + 1 < NCHUNK) {
      const float* wsrc = w + (size_t)(c + 1) * (KC * E_EXP);
#pragma unroll
      for (int j = 0; j < 8; ++j) {
        const int seg = wv * 8 + j;
        load_lds16(wsrc + seg * 256 + lane * 4, &wlds[cur ^ 1][seg * 256]);
      }
    }
    const float* wl = wlds[cur];
    const float* xc = xw + c * KC;

    // software pipeline: prefetch next 4-h x/W while FMA-ing current
    float4 xa[NT];
#pragma unroll
    for (int i = 0; i < NT; ++i) xa[i] = *(const float4*)(xc + i * H_DIM);
    float wa0 = wl[lane], wa1 = wl[64 + lane], wa2 = wl[128 + lane],
          wa3 = wl[192 + lane];

#pragma unroll 2
    for (int h = 0; h < KC; h += 4) {
      const int hn = (h + 4 < KC) ? h + 4 : 0;  // last prefetch harmless
      float4 xb[NT];
#pragma unroll
      for (int i = 0; i < NT; ++i)
        xb[i] = *(const float4*)(xc + i * H_DIM + hn);
      const int wb = hn * 64 + lane;
      float wb0 = wl[wb], wb1 = wl[wb + 64], wb2 = wl[wb + 128],
            wb3 = wl[wb + 192];
#pragma unroll
      for (int i = 0; i < NT; ++i) {
        acc[i] = fmaf(xa[i].x, wa0, acc[i]);
        acc[i] = fmaf(xa[i].y, wa1, acc[i]);
        acc[i] = fmaf(xa[i].z, wa2, acc[i]);
        acc[i] = fmaf(xa[i].w, wa3, acc[i]);
      }
#pragma unroll
      for (int i = 0; i < NT; ++i) xa[i] = xb[i];
      wa0 = wb0; wa1 = wb1; wa2 = wb2; wa3 = wb3;
    }
    cur ^= 1;
  }

  // ---- epilogue: per-token softmax stats + top-2 (lane == expert) ----
  float sumprob = 0.f, cnt = 0.f, lse2 = 0.f;
#pragma unroll
  for (int i = 0; i < NT; ++i) {
    const float v = acc[i];
    float m = v;
#pragma unroll
    for (int d = 1; d < 64; d <<= 1) m = fmaxf(m, __shfl_xor(m, d));
    const float e = expf(v - m);
    float s = e;
#pragma unroll
    for (int d = 1; d < 64; d <<= 1) s += __shfl_xor(s, d);
    const float p = e / s;
    sumprob += p;
    const float lse = m + logf(s);
    lse2 += lse * lse;

    // top-2 on logits (monotone with probs); ties -> lowest index (jax)
    float v1 = v; int i1 = lane;
#pragma unroll
    for (int d = 1; d < 64; d <<= 1) {
      float ov = __shfl_xor(v1, d); int oi = __shfl_xor(i1, d);
      if (ov > v1 || (ov == v1 && oi < i1)) { v1 = ov; i1 = oi; }
    }
    float vx = (lane == i1) ? -__FLT_MAX__ : v;
    float v2 = vx; int i2 = lane;
#pragma unroll
    for (int d = 1; d < 64; d <<= 1) {
      float ov = __shfl_xor(v2, d); int oi = __shfl_xor(i2, d);
      if (ov > v2 || (ov == v2 && oi < i2)) { v2 = ov; i2 = oi; }
    }
    if (lane == 0) {
      const int t = t0 + i;
      out[t * 2] = expf(v1 - m) / s;
      out[t * 2 + 1] = expf(v2 - m) / s;
      out[2 * T_TOK + t * 2] = (float)i1;
      out[2 * T_TOK + t * 2 + 1] = (float)i2;
    }
    cnt += (lane == i1 || lane == i2) ? 1.f : 0.f;
  }

  rsp[wv][lane] = sumprob;
  rcn[wv][lane] = cnt;
  if (lane == 0) rz[wv] = lse2;
  __syncthreads();
  if (tid < 64) {
    float sp = rsp[0][tid] + rsp[1][tid] + rsp[2][tid] + rsp[3][tid];
    float cn = rcn[0][tid] + rcn[1][tid] + rcn[2][tid] + rcn[3][tid];
    float* pb = part + (size_t)blockIdx.x * PART_STRIDE;
    pb[tid] = sp;
    pb[64 + tid] = cn;
    if (tid == 0) pb[128] = rz[0] + rz[1] + rz[2] + rz[3];
  }
}

__global__ __launch_bounds__(256) void router_reduce(
    const float* __restrict__ part, float* __restrict__ out) {
  const int tid = threadIdx.x;
  const int lane = tid & 63;
  const int wv = tid >> 6;
  float sp = 0.f, cn = 0.f, z = 0.f;
  for (int b = wv; b < NBLK; b += NWAVES) {
    const float* pb = part + (size_t)b * PART_STRIDE;
    sp += pb[lane];
    cn += pb[64 + lane];
    z += pb[128];  // wave-uniform accumulate; folded once per wave below
  }
  __shared__ float ssp[NWAVES][64], scn[NWAVES][64], sz[NWAVES];
  ssp[wv][lane] = sp;
  scn[wv][lane] = cn;
  if (lane == 0) sz[wv] = z;
  __syncthreads();
  if (tid < 64) {
    float SP = ssp[0][tid] + ssp[1][tid] + ssp[2][tid] + ssp[3][tid];
    float CN = scn[0][tid] + scn[1][tid] + scn[2][tid] + scn[3][tid];
    float prod = SP * CN;
#pragma unroll
    for (int d = 1; d < 64; d <<= 1) prod += __shfl_xor(prod, d);
    if (tid == 0) {
      const float Z = sz[0] + sz[1] + sz[2] + sz[3];
      const float Tf = (float)T_TOK;
      // aux = 0.01 * (E/K) * sum_e (cnt_e/T) * (sumprob_e/T)
      out[2 * K_TOP * T_TOK] =
          AUX_COEFF * ((float)E_EXP / (float)K_TOP) * prod / (Tf * Tf);
      out[2 * K_TOP * T_TOK + 1] = Z_COEFF * Z / Tf;
    }
  }
}

extern "C" void kernel_launch(void* const* d_in, const int* in_sizes, int n_in,
                              void* d_out, int out_size, void* d_ws,
                              size_t ws_size, hipStream_t stream) {
  const float* x = (const float*)d_in[0];
  const float* w = (const float*)d_in[1];
  float* out = (float*)d_out;
  float* part = (float*)d_ws;
  router_main<<<NBLK, BLOCK, 0, stream>>>(x, w, out, part);
  router_reduce<<<1, 256, 0, stream>>>(part, out);
}

// Round 4
// 217.809 us; speedup vs baseline: 2.1890x; 2.1890x over previous
//
#include <hip/hip_runtime.h>

#define T_TOK 16384
#define H_DIM 2048
#define E_EXP 64
#define AUX_COEFF 0.01f
#define Z_COEFF 0.001f

#define TOKB 16               // tokens per block
#define NBLK (T_TOK / TOKB)   // 1024 blocks
#define BLOCK 256             // 4 waves; wave wv = K-quarter
#define CHUNKS 16             // K chunks of 32 per quarter (4*16*32 = 2048)

// d_ws: wpk uint4[64*8*64] = 512KB; then accb floats:
//   sp[32][64] @ 0, cn[32][64] @ 2048, z[64] @ 4096  -> 4160 floats
#define WPK_U4 (64 * 8 * 64)
#define ACC_OFF ((size_t)WPK_U4 * 16)
#define ACC_N 4160

typedef __attribute__((ext_vector_type(8))) short short8;
typedef __attribute__((ext_vector_type(4))) float f32x4;

__device__ __forceinline__ unsigned bf16rne(float f) {
  unsigned u = __float_as_uint(f);
  return (u + 0x7fffu + ((u >> 16) & 1u)) >> 16;
}

// 3-way bf16 split of 8 floats: x ~= ah + am + al (24-bit effective mantissa)
__device__ __forceinline__ void cvt3(const f32x4 a, const f32x4 b, short8& ah,
                                     short8& am, short8& al) {
  float v[8] = {a.x, a.y, a.z, a.w, b.x, b.y, b.z, b.w};
#pragma unroll
  for (int j = 0; j < 8; ++j) {
    unsigned h = bf16rne(v[j]);
    float r1 = v[j] - __uint_as_float(h << 16);
    unsigned m = bf16rne(r1);
    float r2 = r1 - __uint_as_float(m << 16);
    unsigned l = bf16rne(r2);
    ah[j] = (short)h;
    am[j] = (short)m;
    al[j] = (short)l;
  }
}

// ---- pack W -> bf16 hi/lo B-fragments; also zero the accumulators ----
// lane l holds B[k = c*32 + (l>>4)*8 + j][e = n*16 + (l&15)], j = 0..7
__global__ __launch_bounds__(256) void pack_w(const float* __restrict__ w,
                                              uint4* __restrict__ wpk,
                                              float* __restrict__ accb) {
  const int gid = blockIdx.x * 256 + threadIdx.x;
  if (gid < ACC_N) accb[gid] = 0.f;
  const int c = blockIdx.x;  // 0..63
  const int lane = threadIdx.x & 63;
  const int n = threadIdx.x >> 6;
  const int g = lane >> 4;
  const int e = n * 16 + (lane & 15);
  unsigned hi[8], lo[8];
#pragma unroll
  for (int j = 0; j < 8; ++j) {
    float v = w[(size_t)(c * 32 + g * 8 + j) * E_EXP + e];
    unsigned h = bf16rne(v);
    hi[j] = h;
    lo[j] = bf16rne(v - __uint_as_float(h << 16));
  }
  uint4 H, L;
  H.x = hi[0] | (hi[1] << 16); H.y = hi[2] | (hi[3] << 16);
  H.z = hi[4] | (hi[5] << 16); H.w = hi[6] | (hi[7] << 16);
  L.x = lo[0] | (lo[1] << 16); L.y = lo[2] | (lo[3] << 16);
  L.z = lo[4] | (lo[5] << 16); L.w = lo[6] | (lo[7] << 16);
  wpk[((size_t)c * 8 + n * 2) * 64 + lane] = H;
  wpk[((size_t)c * 8 + n * 2 + 1) * 64 + lane] = L;
}

#define MFMA __builtin_amdgcn_mfma_f32_16x16x32_bf16

// one K-chunk: convert x slot, prefetch next x slot, 20 MFMAs, prefetch next B
#define HALF(X0, X1, BQ, cc, pf)                                            \
  do {                                                                      \
    short8 ah_, am_, al_;                                                   \
    cvt3(X0, X1, ah_, am_, al_);                                            \
    if (pf) {                                                               \
      X0 = *(const f32x4*)(xb + ((cc) + 2) * 32);                           \
      X1 = *(const f32x4*)(xb + ((cc) + 2) * 32 + 4);                       \
    }                                                                       \
    _Pragma("unroll") for (int n_ = 0; n_ < 4; ++n_) {                      \
      short8 bh_ = __builtin_bit_cast(short8, BQ[n_ * 2]);                  \
      short8 bl_ = __builtin_bit_cast(short8, BQ[n_ * 2 + 1]);              \
      acc[n_] = MFMA(al_, bh_, acc[n_], 0, 0, 0);                           \
      acc[n_] = MFMA(am_, bl_, acc[n_], 0, 0, 0);                           \
      acc[n_] = MFMA(am_, bh_, acc[n_], 0, 0, 0);                           \
      acc[n_] = MFMA(ah_, bl_, acc[n_], 0, 0, 0);                           \
      acc[n_] = MFMA(ah_, bh_, acc[n_], 0, 0, 0);                           \
    }                                                                       \
    if (pf) {                                                               \
      _Pragma("unroll") for (int f_ = 0; f_ < 8; ++f_)                      \
          BQ[f_] = wb[((cc) + 2) * 512 + f_ * 64];                          \
    }                                                                       \
  } while (0)

__global__ __launch_bounds__(BLOCK, 2) void router_main(
    const float* __restrict__ x, const uint4* __restrict__ wpk,
    float* __restrict__ out, float* __restrict__ accb) {
  __shared__ float ldst[4][TOKB][E_EXP];  // per-kq partial logits, 16KB
  __shared__ float rsp[4][64], rcn[4][64], rz[4];

  const int tid = threadIdx.x, lane = tid & 63, wv = tid >> 6;
  const int r = lane & 15, g = lane >> 4;
  const int t0 = blockIdx.x * TOKB;

  // A source: token t0+r, K-quarter wv, fragment k-offset g*8 (+imm per chunk)
  const float* xb = x + (size_t)(t0 + r) * H_DIM + wv * 512 + g * 8;
  // B source: chunk stride 512 uint4; per-lane offset `lane`
  const uint4* wb = wpk + (size_t)(wv * 16) * 512 + lane;

  f32x4 acc[4];
#pragma unroll
  for (int n = 0; n < 4; ++n) acc[n] = f32x4{0.f, 0.f, 0.f, 0.f};

  f32x4 xA0 = *(const f32x4*)(xb);
  f32x4 xA1 = *(const f32x4*)(xb + 4);
  f32x4 xB0 = *(const f32x4*)(xb + 32);
  f32x4 xB1 = *(const f32x4*)(xb + 36);
  uint4 BA[8], BB[8];
#pragma unroll
  for (int f = 0; f < 8; ++f) BA[f] = wb[f * 64];
#pragma unroll
  for (int f = 0; f < 8; ++f) BB[f] = wb[512 + f * 64];

  for (int c = 0; c < CHUNKS - 2; c += 2) {
    HALF(xA0, xA1, BA, c, 1);
    HALF(xB0, xB1, BB, c + 1, 1);
  }
  HALF(xA0, xA1, BA, CHUNKS - 2, 0);
  HALF(xB0, xB1, BB, CHUNKS - 1, 0);

  // C-frag -> LDS: D row (token) = g*4+q, D col (expert) = n*16+r  [m89 layout]
#pragma unroll
  for (int n = 0; n < 4; ++n)
#pragma unroll
    for (int q = 0; q < 4; ++q)
      ldst[wv][g * 4 + q][n * 16 + r] = acc[n][q];
  __syncthreads();

  // ---- epilogue: wave wv owns local tokens 4wv..4wv+3; lane == expert ----
  float sumprob = 0.f, cnt = 0.f, lse2 = 0.f;
#pragma unroll
  for (int i = 0; i < 4; ++i) {
    const int tl = wv * 4 + i;
    const float v = ldst[0][tl][lane] + ldst[1][tl][lane] +
                    ldst[2][tl][lane] + ldst[3][tl][lane];
    float m = v;
#pragma unroll
    for (int d = 1; d < 64; d <<= 1) m = fmaxf(m, __shfl_xor(m, d));
    const float e = expf(v - m);
    float s = e;
#pragma unroll
    for (int d = 1; d < 64; d <<= 1) s += __shfl_xor(s, d);
    sumprob += e / s;
    const float lse = m + logf(s);
    lse2 += lse * lse;

    // top-2 on logits (softmax-monotone); ties -> lowest index (jax)
    float v1 = v; int i1 = lane;
#pragma unroll
    for (int d = 1; d < 64; d <<= 1) {
      float ov = __shfl_xor(v1, d); int oi = __shfl_xor(i1, d);
      if (ov > v1 || (ov == v1 && oi < i1)) { v1 = ov; i1 = oi; }
    }
    float vx = (lane == i1) ? -__FLT_MAX__ : v;
    float v2 = vx; int i2 = lane;
#pragma unroll
    for (int d = 1; d < 64; d <<= 1) {
      float ov = __shfl_xor(v2, d); int oi = __shfl_xor(i2, d);
      if (ov > v2 || (ov == v2 && oi < i2)) { v2 = ov; i2 = oi; }
    }
    if (lane == 0) {
      const int t = t0 + tl;
      out[t * 2] = expf(v1 - m) / s;
      out[t * 2 + 1] = expf(v2 - m) / s;
      out[2 * T_TOK + t * 2] = (float)i1;
      out[2 * T_TOK + t * 2 + 1] = (float)i2;
    }
    cnt += (lane == i1 || lane == i2) ? 1.f : 0.f;
  }

  rsp[wv][lane] = sumprob;
  rcn[wv][lane] = cnt;
  if (lane == 0) rz[wv] = lse2;
  __syncthreads();
  if (wv == 0) {
    const float sp4 = rsp[0][lane] + rsp[1][lane] + rsp[2][lane] + rsp[3][lane];
    const float cn4 = rcn[0][lane] + rcn[1][lane] + rcn[2][lane] + rcn[3][lane];
    const int slot = blockIdx.x & 31;
    atomicAdd(&accb[slot * 64 + lane], sp4);
    atomicAdd(&accb[2048 + slot * 64 + lane], cn4);
    if (lane == 0)
      atomicAdd(&accb[4096 + (blockIdx.x & 63)],
                rz[0] + rz[1] + rz[2] + rz[3]);
  }
}

__global__ __launch_bounds__(64) void router_reduce(
    const float* __restrict__ accb, float* __restrict__ out) {
  const int lane = threadIdx.x;
  float SP = 0.f, CN = 0.f;
#pragma unroll
  for (int s = 0; s < 32; ++s) {
    SP += accb[s * 64 + lane];
    CN += accb[2048 + s * 64 + lane];
  }
  float prod = SP * CN;
  float Z = accb[4096 + lane];
#pragma unroll
  for (int d = 1; d < 64; d <<= 1) {
    prod += __shfl_xor(prod, d);
    Z += __shfl_xor(Z, d);
  }
  if (lane == 0) {
    const float Tf = (float)T_TOK;
    out[4 * T_TOK] = AUX_COEFF * ((float)E_EXP / 2.0f) * prod / (Tf * Tf);
    out[4 * T_TOK + 1] = Z_COEFF * Z / Tf;
  }
}

extern "C" void kernel_launch(void* const* d_in, const int* in_sizes, int n_in,
                              void* d_out, int out_size, void* d_ws,
                              size_t ws_size, hipStream_t stream) {
  const float* x = (const float*)d_in[0];
  const float* w = (const float*)d_in[1];
  float* out = (float*)d_out;
  uint4* wpk = (uint4*)d_ws;
  float* accb = (float*)((char*)d_ws + ACC_OFF);

  pack_w<<<64, 256, 0, stream>>>(w, wpk, accb);
  router_main<<<NBLK, BLOCK, 0, stream>>>(x, wpk, out, accb);
  router_reduce<<<1, 64, 0, stream>>>(accb, out);
}